// Round 7
// baseline (191.768 us; speedup 1.0000x reference)
//
#include <hip/hip_runtime.h>
#include <hip/hip_bf16.h>

// SegFormerXAttention: B=2, LV=1024, LT=512, D=1024, H=16, DH=64
#define NH 16

typedef __attribute__((ext_vector_type(4))) float f32x4;
typedef __attribute__((ext_vector_type(8))) __bf16 bf16x8;

#define SCL2E 0.18033688011112042f   // (1/sqrt(64)) * log2(e)

__device__ __forceinline__ short f2bs(float f) {
  union { __bf16 h; short s; } x; x.h = (__bf16)f; return x.s;
}
__device__ __forceinline__ unsigned pack2(float a, float b) {
  union { __bf16 h[2]; unsigned u; } x;
  x.h[0] = (__bf16)a; x.h[1] = (__bf16)b; return x.u;
}

__device__ __forceinline__ f32x4 mfma16(bf16x8 a, bf16x8 b, f32x4 c) {
  return __builtin_amdgcn_mfma_f32_16x16x32_bf16(a, b, c, 0, 0, 0);
}

// async global->LDS, 16B per lane. LDS dest = wave-uniform base + lane*16.
__device__ __forceinline__ void gload16(const void* g, void* lds) {
  __builtin_amdgcn_global_load_lds(
      (const __attribute__((address_space(1))) void*)(unsigned long long)(g),
      (__attribute__((address_space(3))) void*)(unsigned)(unsigned long long)(lds),
      16, 0, 0);
}

// ---------------- convert f32 -> bf16 ----------------
__global__ __launch_bounds__(256) void conv_kernel(const float* __restrict__ src,
                                                   short* __restrict__ dst, int n4) {
  int i = blockIdx.x * 256 + threadIdx.x;
  if (i >= n4) return;
  float4 v = *(const float4*)(src + (size_t)i * 4);
  *(uint2*)(dst + (size_t)i * 4) = make_uint2(pack2(v.x, v.y), pack2(v.z, v.w));
}

// ---------------- combined key mask -> additive float mask [B][1536] ----------------
__global__ void kmask_kernel(const int* __restrict__ vm, const int* __restrict__ um,
                             float* __restrict__ kmf) {
  int i = blockIdx.x * 256 + threadIdx.x;
  if (i >= 2 * 1536) return;
  int b = i / 1536, k = i - b * 1536;
  int valid = (k < 1024) ? vm[b * 1024 + k] : um[b * 512 + (k - 1024)];
  kmf[i] = valid ? 0.0f : -1e35f;
}

// ---------------- weight transpose f32[K,N] -> bf16[N,K] (Q weights pre-scaled) ----------------
struct WPtrs { const float* s[14]; };

__global__ __launch_bounds__(256) void wtrans_kernel(WPtrs p, short* __restrict__ wt) {
  __shared__ float t[64][65];
  int z = blockIdx.z;
  const float* src = p.s[z];
  short* dst = wt + (size_t)z * 1024 * 1024;
  float scl = (z == 0 || z == 3 || z == 6 || z == 9) ? SCL2E : 1.0f;  // Q projections
  int kb = blockIdx.y * 64, nb = blockIdx.x * 64;
  int c = threadIdx.x & 63, r0 = threadIdx.x >> 6;
  #pragma unroll
  for (int i = 0; i < 16; i++) {
    int r = r0 + i * 4;
    t[r][c] = src[(size_t)(kb + r) * 1024 + nb + c];
  }
  __syncthreads();
  #pragma unroll
  for (int i = 0; i < 16; i++) {
    int r = r0 + i * 4;
    dst[(size_t)(nb + r) * 1024 + kb + c] = f2bs(t[c][r] * scl);
  }
}

// ---------------- GEMM staging: tile [128 rows][32 k] bf16 = 8KB, swizzled source ----------------
__device__ __forceinline__ void stage_g(const short* __restrict__ src, int row0, int kt,
                                        short* buf, int tid) {
  int w = tid >> 6;
  #pragma unroll
  for (int i = 0; i < 2; i++) {
    int s = i * 256 + tid;
    int row = s >> 2, c = s & 3;
    int cs = c ^ (row & 3);
    gload16(src + (size_t)(row0 + row) * 1024 + kt + cs * 8,
            buf + (size_t)(i * 256 + w * 64) * 8);
  }
}

// ---------------- 128x128 bf16 GEMM mainloop (K=1024, BK=32, dbuf, counted-vmcnt) ----------------
// T4: stage(next) -> vmcnt(4) [= in-flight instrs for next tile] -> raw s_barrier.
// Prefetch stays in flight ACROSS the barrier (no vmcnt(0) drain). In-loop VMEM budget:
// exactly 4 gload16 per wave per iter (all other VMEM is outside the loop).
__device__ __forceinline__ void gemm_128(const short* __restrict__ X, const short* __restrict__ W,
                                         short* As, short* Bs,
                                         f32x4 (&acc)[4][4], int mb0, int nb0) {
  int tid = threadIdx.x;
  int lane = tid & 63, g = lane >> 4, r16 = lane & 15, w = tid >> 6;
  int wr = (w >> 1) * 64, wc = (w & 1) * 64;
  int cs8 = (g ^ (r16 & 3)) * 8;
  stage_g(X, mb0, 0, As, tid);
  stage_g(W, nb0, 0, Bs, tid);
  int cur = 0;
  for (int kt = 0; kt < 1024; kt += 32) {
    if (kt + 32 < 1024) {
      stage_g(X, mb0, kt + 32, As + (cur ^ 1) * 4096, tid);
      stage_g(W, nb0, kt + 32, Bs + (cur ^ 1) * 4096, tid);
      asm volatile("s_waitcnt vmcnt(4)" ::: "memory");   // current tile's DMA done
    } else {
      asm volatile("s_waitcnt vmcnt(0)" ::: "memory");   // tail: drain all
    }
    __builtin_amdgcn_s_barrier();
    __builtin_amdgcn_sched_barrier(0);
    const short* a = As + cur * 4096;
    const short* bb = Bs + cur * 4096;
    bf16x8 af[4], bfv[4];
    #pragma unroll
    for (int i = 0; i < 4; i++) af[i]  = *(const bf16x8*)&a[(wr + i * 16 + r16) * 32 + cs8];
    #pragma unroll
    for (int i = 0; i < 4; i++) bfv[i] = *(const bf16x8*)&bb[(wc + i * 16 + r16) * 32 + cs8];
    __builtin_amdgcn_s_setprio(1);
    #pragma unroll
    for (int i = 0; i < 4; i++)
      #pragma unroll
      for (int j = 0; j < 4; j++)
        acc[i][j] = mfma16(af[i], bfv[j], acc[i][j]);
    __builtin_amdgcn_s_setprio(0);
    __builtin_amdgcn_sched_barrier(0);
    __builtin_amdgcn_s_barrier();    // WAR: next stage writes 'cur' only after all reads done
    cur ^= 1;
  }
}

// ---------------- projection GEMMs (12 jobs in ONE launch via flattened grid) ----------------
struct ProjJobs {
  const short* wt[12];
  short* dst[12];
  const float* bias[12];
  float bscl[12];
  int mode[12];    // 0 = QK layout [B,H,lrows,64] (+row off), 1 = V^T layout [B,H,64,1536] (+col off)
  int lrows[12];
  int off[12];
  int mt[12];      // M tiles (M/128)
  int lqs[12];     // log2(LQ)
  int src[12];     // 0 = Xv, 1 = Xu
};

__global__ __launch_bounds__(256) void proj_gemm(const short* __restrict__ Xv,
                                                 const short* __restrict__ Xu, ProjJobs jb) {
  __shared__ short As[2 * 4096];
  __shared__ short Bs[2 * 4096];
  int w0 = (blockIdx.z * gridDim.y + blockIdx.y) * gridDim.x + blockIdx.x;
  int nwg = gridDim.x * gridDim.y * gridDim.z;
  int f = (w0 & 7) * (nwg >> 3) + (w0 >> 3);
  int gxy = gridDim.x * gridDim.y;
  int jz = f / gxy;
  int rem = f - jz * gxy;
  int mt = rem >> 3;
  if (mt >= jb.mt[jz]) return;             // usr jobs: M=1024 only
  int mb0 = mt * 128, nb0 = (rem & 7) * 128;
  const short* X = jb.src[jz] ? Xu : Xv;
  int lqShift = jb.lqs[jz];
  f32x4 acc[4][4];
  f32x4 zf = {0.f, 0.f, 0.f, 0.f};
  #pragma unroll
  for (int i = 0; i < 4; i++)
    #pragma unroll
    for (int j = 0; j < 4; j++) acc[i][j] = zf;
  gemm_128(X, jb.wt[jz], As, Bs, acc, mb0, nb0);

  int tid = threadIdx.x, lane = tid & 63, g = lane >> 4, r16 = lane & 15, w = tid >> 6;
  int wr = (w >> 1) * 64, wc = (w & 1) * 64;
  const float* bias = jb.bias[jz];
  float bscl = jb.bscl[jz];
  short* dst = jb.dst[jz];
  int mode = jb.mode[jz], lrows = jb.lrows[jz], off = jb.off[jz];
  int lqMask = (1 << lqShift) - 1;
  #pragma unroll
  for (int i = 0; i < 4; i++) {
    int m0 = mb0 + wr + i * 16 + g * 4;
    #pragma unroll
    for (int j = 0; j < 4; j++) {
      int n = nb0 + wc + j * 16 + r16;
      float bv = bias[n] * bscl;
      int h = n >> 6, d = n & 63;
      if (mode == 0) {
        #pragma unroll
        for (int r = 0; r < 4; r++) {
          int m = m0 + r;
          int b = m >> lqShift, l = m & lqMask;
          dst[((size_t)(b * NH + h) * lrows + off + l) * 64 + d] = f2bs(acc[i][j][r] + bv);
        }
      } else {
        int b = m0 >> lqShift, l = m0 & lqMask;
        size_t base = ((size_t)(b * NH + h) * 64 + d) * 1536 + off + l;
        *(uint2*)(dst + base) = make_uint2(pack2(acc[i][j][0] + bv, acc[i][j][1] + bv),
                                           pack2(acc[i][j][2] + bv, acc[i][j][3] + bv));
      }
    }
  }
}

// ---------------- FF GEMM (2 jobs in one launch): out = A@W + bias + resid (f32 out) ----------------
struct FfJobs {
  const short* A[2];
  const short* W[2];
  const float* bias[2];
  const float* resid[2];
  float* out[2];
  int mt[2];
};

__global__ __launch_bounds__(256) void ff_gemm(FfJobs jb) {
  __shared__ short As[2 * 4096];
  __shared__ short Bs[2 * 4096];
  int w0 = (blockIdx.z * gridDim.y + blockIdx.y) * gridDim.x + blockIdx.x;
  int nwg = gridDim.x * gridDim.y * gridDim.z;
  int f = (w0 & 7) * (nwg >> 3) + (w0 >> 3);
  int gxy = gridDim.x * gridDim.y;
  int jz = f / gxy;
  int rem = f - jz * gxy;
  int mt = rem >> 3;
  if (mt >= jb.mt[jz]) return;
  int mb0 = mt * 128, nb0 = (rem & 7) * 128;
  f32x4 acc[4][4];
  f32x4 zf = {0.f, 0.f, 0.f, 0.f};
  #pragma unroll
  for (int i = 0; i < 4; i++)
    #pragma unroll
    for (int j = 0; j < 4; j++) acc[i][j] = zf;
  gemm_128(jb.A[jz], jb.W[jz], As, Bs, acc, mb0, nb0);

  int tid = threadIdx.x, lane = tid & 63, g = lane >> 4, r16 = lane & 15, w = tid >> 6;
  int wr = (w >> 1) * 64, wc = (w & 1) * 64;
  const float* bias = jb.bias[jz];
  const float* resid = jb.resid[jz];
  float* out = jb.out[jz];
  #pragma unroll
  for (int i = 0; i < 4; i++) {
    int m0 = mb0 + wr + i * 16 + g * 4;
    #pragma unroll
    for (int j = 0; j < 4; j++) {
      int n = nb0 + wc + j * 16 + r16;
      float bv = bias[n];
      #pragma unroll
      for (int r = 0; r < 4; r++) {
        size_t idx = (size_t)(m0 + r) * 1024 + n;
        out[idx] = acc[i][j][r] + bv + resid[idx];
      }
    }
  }
}

// ---------------- attention staging ----------------
__device__ __forceinline__ void stage_k(const short* __restrict__ Kb, int kb, short* buf, int tid) {
  int w = tid >> 6;
  #pragma unroll
  for (int i = 0; i < 2; i++) {
    int s = i * 256 + tid;
    int row = s >> 3, c = s & 7;
    int cs = c ^ (row & 7);
    gload16(Kb + (size_t)(kb + row) * 64 + cs * 8,
            buf + (size_t)(i * 256 + w * 64) * 8);
  }
}
__device__ __forceinline__ void stage_v(const short* __restrict__ Vb, int kb, short* buf, int tid) {
  int w = tid >> 6;
  #pragma unroll
  for (int i = 0; i < 2; i++) {
    int s = i * 256 + tid;
    int row = s >> 3, c = s & 7;       // row = dh
    int cs = c ^ (row & 7);
    gload16(Vb + (size_t)row * 1536 + kb + cs * 8,
            buf + (size_t)(i * 256 + w * 64) * 8);
  }
}

// ---------------- fused masked attention: key-split 2-way, no-max softmax, counted-vmcnt ----------------
struct AttnArgs {
  const short *Qva, *Qvb, *Kv, *VvT;
  const short *Qta, *Qtb, *Kt, *VtT;
  const int *vmask, *umask;
  const float *kmaskf;
  float *PO, *PL;
};

__global__ __launch_bounds__(256) void attn_kernel(AttnArgs A) {
  __shared__ short Ks[2][64 * 64];   // 16 KB
  __shared__ short Vs[2][64 * 64];   // 16 KB
  __shared__ short Ps[4][16 * 36];   // 4.5 KB per-wave P tile (per-kk reuse), stride 36
  __shared__ float kms[768];         // 3 KB additive mask for this key half

  int w0 = blockIdx.x;               // 1536 blocks
  int fidx = (w0 & 7) * 192 + (w0 >> 3);   // XCD-chunk swizzle
  int half = fidx & 1;
  int slot = fidx >> 1;              // (b*16+h)*24 + xx
  int xx = slot % 24;
  int hs = slot / 24;
  int h = hs & 15;
  int b = hs >> 4;
  bool isV = xx < 16;
  int qt = isV ? xx : (xx - 16);
  int LQ = isV ? 1024 : 512;
  const short* Qa = isV ? A.Qva : A.Qta;
  const short* Qb = isV ? A.Qvb : A.Qtb;
  const short* K  = isV ? A.Kv  : A.Kt;
  const short* VT = isV ? A.VvT : A.VtT;
  const int* qmask = isV ? A.vmask : A.umask;

  int tid = threadIdx.x, w = tid >> 6, lane = tid & 63, g = lane >> 4, r16 = lane & 15;
  int q = qt * 64 + w * 16 + r16;
  size_t bh = (size_t)b * NH + h;
  int k0base = half * 768;

  const short* qpa = Qa + (bh * LQ + q) * 64 + g * 8;
  const short* qpb = Qb + (bh * LQ + q) * 64 + g * 8;
  bf16x8 qa0 = *(const bf16x8*)qpa;
  bf16x8 qa1 = *(const bf16x8*)(qpa + 32);
  bf16x8 qb0 = *(const bf16x8*)qpb;
  bf16x8 qb1 = *(const bf16x8*)(qpb + 32);
  int mqi = qmask[b * LQ + q];

  const short* Kb = K + bh * (size_t)(1536 * 64);
  const short* Vb = VT + bh * (size_t)(64 * 1536);
  const float* kmb = A.kmaskf + b * 1536 + k0base;
  #pragma unroll
  for (int s = tid; s < 192; s += 256)
    *(float4*)&kms[s * 4] = *(const float4*)(kmb + s * 4);
  asm volatile("s_waitcnt lgkmcnt(0)" ::: "memory");   // kms ds_writes visible before barrier1

  short* pw = &Ps[w][r16 * 36];
  int sw8 = r16 & 7;

  bf16x8 ones;
  #pragma unroll
  for (int i = 0; i < 8; i++) ones[i] = (__bf16)1.0f;

  f32x4 o[4];
  f32x4 lacc;
  f32x4 zf = {0.f, 0.f, 0.f, 0.f};
  #pragma unroll
  for (int i = 0; i < 4; i++) o[i] = zf;
  lacc = zf;

  stage_k(Kb, k0base, Ks[0], tid);
  stage_v(Vb, k0base, Vs[0], tid);
  int cur = 0;
  for (int kb2 = 0; kb2 < 768; kb2 += 64) {
    if (kb2 + 64 < 768) {
      stage_k(Kb, k0base + kb2 + 64, Ks[cur ^ 1], tid);
      stage_v(Vb, k0base + kb2 + 64, Vs[cur ^ 1], tid);
      asm volatile("s_waitcnt vmcnt(4)" ::: "memory");   // current K/V DMA done
    } else {
      asm volatile("s_waitcnt vmcnt(0)" ::: "memory");
    }
    __builtin_amdgcn_s_barrier();
    __builtin_amdgcn_sched_barrier(0);
    const short* Kc = Ks[cur];
    const short* Vc = Vs[cur];
    int gk = k0base + kb2;
    bf16x8 q0 = (gk < 1024) ? qa0 : qb0;
    bf16x8 q1 = (gk < 1024) ? qa1 : qb1;

    float p[16];
    #pragma unroll
    for (int ko = 0; ko < 4; ko++) {
      int krow = ko * 16 + r16;
      bf16x8 k0f = *(const bf16x8*)&Kc[krow * 64 + ((g ^ sw8) * 8)];
      bf16x8 k1f = *(const bf16x8*)&Kc[krow * 64 + (((4 + g) ^ sw8) * 8)];
      __builtin_amdgcn_s_setprio(1);
      f32x4 s = mfma16(k0f, q0, zf);
      s = mfma16(k1f, q1, s);
      __builtin_amdgcn_s_setprio(0);
      float4 kf = *(const float4*)&kms[kb2 + ko * 16 + g * 4];
      p[ko * 4 + 0] = exp2f(mqi ? s[0] + kf.x : 0.0f);
      p[ko * 4 + 1] = exp2f(mqi ? s[1] + kf.y : 0.0f);
      p[ko * 4 + 2] = exp2f(mqi ? s[2] + kf.z : 0.0f);
      p[ko * 4 + 3] = exp2f(mqi ? s[3] + kf.w : 0.0f);
    }

    #pragma unroll
    for (int kk = 0; kk < 2; kk++) {
      int pB = kk * 8;
      *(uint2*)(pw + g * 4) =
          make_uint2(pack2(p[pB + 0], p[pB + 1]), pack2(p[pB + 2], p[pB + 3]));
      *(uint2*)(pw + 16 + g * 4) =
          make_uint2(pack2(p[pB + 4], p[pB + 5]), pack2(p[pB + 6], p[pB + 7]));
      bf16x8 pb = *(const bf16x8*)(pw + g * 8);
      __builtin_amdgcn_s_setprio(1);
      #pragma unroll
      for (int dg = 0; dg < 4; dg++) {
        bf16x8 vfrag = *(const bf16x8*)&Vc[(dg * 16 + r16) * 64 + (((kk * 4 + g) ^ sw8) * 8)];
        o[dg] = mfma16(vfrag, pb, o[dg]);
      }
      lacc = mfma16(ones, pb, lacc);
      __builtin_amdgcn_s_setprio(0);
    }
    __builtin_amdgcn_sched_barrier(0);
    __builtin_amdgcn_s_barrier();    // WAR: next stage overwrites 'cur' only after reads done
    cur ^= 1;
  }
  // partials: PO[slot][half][q(64)][d(64)] f32, PL[slot][half][q]
  float* po = A.PO + ((size_t)slot * 2 + half) * 4096 + (w * 16 + r16) * 64;
  #pragma unroll
  for (int dg = 0; dg < 4; dg++)
    *(f32x4*)(po + dg * 16 + g * 4) = o[dg];
  if (g == 0)
    A.PL[((size_t)slot * 2 + half) * 64 + w * 16 + r16] = lacc[0];
}

// ---------------- combine: o = (o0+o1)/(l0+l1), write bf16 AO ----------------
__global__ __launch_bounds__(256) void attn_combine(const float* __restrict__ PO,
                                                    const float* __restrict__ PL,
                                                    short* __restrict__ AOv,
                                                    short* __restrict__ AOu) {
  __shared__ float linv[64];
  int w0 = blockIdx.x;               // 768 blocks
  int slot = (w0 & 7) * 96 + (w0 >> 3);   // matches attn XCD placement
  int tid = threadIdx.x;
  const float* p0 = PO + (size_t)slot * 2 * 4096;
  const float* p1 = p0 + 4096;
  if (tid < 64) {
    float l = PL[(size_t)slot * 2 * 64 + tid] + PL[((size_t)slot * 2 + 1) * 64 + tid];
    linv[tid] = 1.0f / l;
  }
  __syncthreads();
  int xx = slot % 24;
  int hs = slot / 24;
  int h = hs & 15;
  int b = hs >> 4;
  bool isV = xx < 16;
  int qt = isV ? xx : (xx - 16);
  int LQ = isV ? 1024 : 512;
  short* out = isV ? AOv : AOu;
  #pragma unroll
  for (int it = 0; it < 8; it++) {
    int idx = (it * 256 + tid) * 2;
    int q = idx >> 6, d = idx & 63;
    float2 a = *(const float2*)(p0 + idx);
    float2 c = *(const float2*)(p1 + idx);
    float li = linv[q];
    *(unsigned*)(out + ((size_t)b * LQ + qt * 64 + q) * 1024 + h * 64 + d) =
        pack2((a.x + c.x) * li, (a.y + c.y) * li);
  }
}

// ---------------- in-place LayerNorm over rows of 1024 ----------------
__global__ __launch_bounds__(256) void ln_kernel(float* __restrict__ y, const float* __restrict__ gam,
                                                 const float* __restrict__ bet) {
  __shared__ float sh[8];
  size_t row = blockIdx.x;
  int tid = threadIdx.x;
  float4 v = *(const float4*)(y + row * 1024 + tid * 4);
  float s = v.x + v.y + v.z + v.w;
  float ss = v.x * v.x + v.y * v.y + v.z * v.z + v.w * v.w;
  #pragma unroll
  for (int off = 32; off >= 1; off >>= 1) {
    s += __shfl_xor(s, off);
    ss += __shfl_xor(ss, off);
  }
  int w = tid >> 6;
  if ((tid & 63) == 0) { sh[w] = s; sh[4 + w] = ss; }
  __syncthreads();
  float st = sh[0] + sh[1] + sh[2] + sh[3];
  float sst = sh[4] + sh[5] + sh[6] + sh[7];
  float mu = st * (1.0f / 1024.0f);
  float var = sst * (1.0f / 1024.0f) - mu * mu;
  float rs = rsqrtf(var + 1e-12f);
  float4 gv = *(const float4*)(gam + tid * 4);
  float4 bv = *(const float4*)(bet + tid * 4);
  float4 ov;
  ov.x = (v.x - mu) * rs * gv.x + bv.x;
  ov.y = (v.y - mu) * rs * gv.y + bv.y;
  ov.z = (v.z - mu) * rs * gv.z + bv.z;
  ov.w = (v.w - mu) * rs * gv.w + bv.w;
  *(float4*)(y + row * 1024 + tid * 4) = ov;
}

extern "C" void kernel_launch(void* const* d_in, const int* in_sizes, int n_in,
                              void* d_out, int out_size, void* d_ws, size_t ws_size,
                              hipStream_t stream) {
  const float* vid_feat = (const float*)d_in[0];
  const float* usr_feat = (const float*)d_in[1];
  const int* vid_mask = (const int*)d_in[2];
  const int* usr_mask = (const int*)d_in[3];
  const float* v2v_W = (const float*)d_in[4];
  const float* v2v_b = (const float*)d_in[5];
  const float* t2v_W = (const float*)d_in[6];
  const float* t2v_b = (const float*)d_in[7];
  const float* v2t_W = (const float*)d_in[8];
  const float* v2t_b = (const float*)d_in[9];
  const float* t2t_W = (const float*)d_in[10];
  const float* t2t_b = (const float*)d_in[11];
  const float* ffu_W = (const float*)d_in[12];
  const float* ffu_b = (const float*)d_in[13];
  const float* ffv_W = (const float*)d_in[14];
  const float* ffv_b = (const float*)d_in[15];
  const float* lnu_g = (const float*)d_in[16];
  const float* lnu_b = (const float*)d_in[17];
  const float* lnv_g = (const float*)d_in[18];
  const float* lnv_b = (const float*)d_in[19];

  const size_t WM = 1024 * 1024;
  char* ws = (char*)d_ws;
  size_t off = 0;
  auto alloc = [&](size_t bytes) -> void* {
    void* p = ws + off;
    off += (bytes + 255) & ~(size_t)255;
    return p;
  };
  short* Xv  = (short*)alloc((size_t)2048 * 1024 * 2);
  short* Xu  = (short*)alloc((size_t)1024 * 1024 * 2);
  short* Wt  = (short*)alloc((size_t)14 * WM * 2);
  short* Qva = (short*)alloc((size_t)2 * NH * 1024 * 64 * 2);
  short* Qvb = (short*)alloc((size_t)2 * NH * 1024 * 64 * 2);
  short* Kv  = (short*)alloc((size_t)2 * NH * 1536 * 64 * 2);
  short* VvT = (short*)alloc((size_t)2 * NH * 64 * 1536 * 2);
  short* Qta = (short*)alloc((size_t)2 * NH * 512 * 64 * 2);
  short* Qtb = (short*)alloc((size_t)2 * NH * 512 * 64 * 2);
  short* Kt  = (short*)alloc((size_t)2 * NH * 1536 * 64 * 2);
  short* VtT = (short*)alloc((size_t)2 * NH * 64 * 1536 * 2);
  short* AOv = (short*)alloc((size_t)2048 * 1024 * 2);
  short* AOu = (short*)alloc((size_t)1024 * 1024 * 2);
  float* kmf = (float*)alloc((size_t)2 * 1536 * 4);
  float* PO  = (float*)alloc((size_t)768 * 2 * 4096 * 4);   // 25.2 MB partial O
  float* PL  = (float*)alloc((size_t)768 * 2 * 64 * 4);     // partial l

  // 1) convert activations + additive key mask
  conv_kernel<<<2048, 256, 0, stream>>>(vid_feat, Xv, 2048 * 1024 / 4);
  conv_kernel<<<1024, 256, 0, stream>>>(usr_feat, Xu, 1024 * 1024 / 4);
  kmask_kernel<<<12, 256, 0, stream>>>(vid_mask, usr_mask, kmf);

  // 2) transpose weights -> bf16 [N,K] (Q weights scaled by SCL2E)
  WPtrs wp;
  wp.s[0] = v2v_W; wp.s[1] = v2v_W + WM; wp.s[2] = v2v_W + 2 * WM;
  wp.s[3] = t2v_W; wp.s[4] = t2v_W + WM; wp.s[5] = t2v_W + 2 * WM;
  wp.s[6] = v2t_W; wp.s[7] = v2t_W + WM; wp.s[8] = v2t_W + 2 * WM;
  wp.s[9] = t2t_W; wp.s[10] = t2t_W + WM; wp.s[11] = t2t_W + 2 * WM;
  wp.s[12] = ffu_W; wp.s[13] = ffv_W;
  wtrans_kernel<<<dim3(16, 16, 14), 256, 0, stream>>>(wp, Wt);

  // 3) projection GEMMs: 12 jobs, one launch
  ProjJobs jp;
  jp.wt[0] = Wt + 0 * WM;  jp.dst[0] = Qva; jp.bias[0] = v2v_b;        jp.bscl[0] = SCL2E; jp.mode[0] = 0; jp.lrows[0] = 1024; jp.off[0] = 0;
  jp.wt[1] = Wt + 1 * WM;  jp.dst[1] = Kv;  jp.bias[1] = v2v_b + 1024; jp.bscl[1] = 1.0f;  jp.mode[1] = 0; jp.lrows[1] = 1536; jp.off[1] = 0;
  jp.wt[2] = Wt + 2 * WM;  jp.dst[2] = VvT; jp.bias[2] = v2v_b + 2048; jp.bscl[2] = 1.0f;  jp.mode[2] = 1; jp.lrows[2] = 0;    jp.off[2] = 0;
  jp.wt[3] = Wt + 3 * WM;  jp.dst[3] = Qvb; jp.bias[3] = t2v_b;        jp.bscl[3] = SCL2E; jp.mode[3] = 0; jp.lrows[3] = 1024; jp.off[3] = 0;
  jp.wt[4] = Wt + 7 * WM;  jp.dst[4] = Kt;  jp.bias[4] = v2t_b + 1024; jp.bscl[4] = 1.0f;  jp.mode[4] = 0; jp.lrows[4] = 1536; jp.off[4] = 0;
  jp.wt[5] = Wt + 8 * WM;  jp.dst[5] = VtT; jp.bias[5] = v2t_b + 2048; jp.bscl[5] = 1.0f;  jp.mode[5] = 1; jp.lrows[5] = 0;    jp.off[5] = 0;
  jp.wt[6] = Wt + 4 * WM;  jp.dst[6] = Kv;  jp.bias[6] = t2v_b + 1024; jp.bscl[6] = 1.0f;  jp.mode[6] = 0; jp.lrows[6] = 1536; jp.off[6] = 1024;
  jp.wt[7] = Wt + 5 * WM;  jp.dst[7] = VvT; jp.bias[7] = t2v_b + 2048; jp.bscl[7] = 1.0f;  jp.mode[7] = 1; jp.lrows[7] = 0;    jp.off[7] = 1024;
  jp.wt[8] = Wt + 6 * WM;  jp.dst[8] = Qta; jp.bias[8] = v2t_b;        jp.bscl[8] = SCL2E; jp.mode[8] = 0; jp.lrows[8] = 512;  jp.off[8] = 0;
  jp.wt[9] = Wt + 9 * WM;  jp.dst[9] = Qtb; jp.bias[9] = t2t_b;        jp.bscl[9] = SCL2E; jp.mode[9] = 0; jp.lrows[9] = 512;  jp.off[9] = 0;
  jp.wt[10] = Wt + 10 * WM; jp.dst[10] = Kt;  jp.bias[10] = t2t_b + 1024; jp.bscl[10] = 1.0f; jp.mode[10] = 0; jp.lrows[10] = 1536; jp.off[10] = 1024;
  jp.wt[11] = Wt + 11 * WM; jp.dst[11] = VtT; jp.bias[11] = t2t_b + 2048; jp.bscl[11] = 1.0f; jp.mode[11] = 1; jp.lrows[11] = 0;    jp.off[11] = 1024;
  for (int i = 0; i < 6; i++)  { jp.mt[i] = 16; jp.lqs[i] = 10; jp.src[i] = 0; }
  for (int i = 6; i < 12; i++) { jp.mt[i] = 8;  jp.lqs[i] = 9;  jp.src[i] = 1; }
  proj_gemm<<<dim3(8, 16, 12), 256, 0, stream>>>(Xv, Xu, jp);

  // 4) attention: key-split 2-way, then combine
  AttnArgs aa;
  aa.Qva = Qva; aa.Qvb = Qvb; aa.Kv = Kv; aa.VvT = VvT;
  aa.Qta = Qta; aa.Qtb = Qtb; aa.Kt = Kt; aa.VtT = VtT;
  aa.vmask = vid_mask; aa.umask = usr_mask; aa.kmaskf = kmf;
  aa.PO = PO; aa.PL = PL;
  attn_kernel<<<1536, 256, 0, stream>>>(aa);
  attn_combine<<<768, 256, 0, stream>>>(PO, PL, AOv, AOu);

  // 5) FF + residual (one launch), then LayerNorm in place
  float* out_v = (float*)d_out;
  float* out_u = (float*)d_out + (size_t)2 * 1024 * 1024;
  FfJobs jf;
  jf.A[0] = AOv; jf.W[0] = Wt + 13 * WM; jf.bias[0] = ffv_b; jf.resid[0] = vid_feat; jf.out[0] = out_v; jf.mt[0] = 16;
  jf.A[1] = AOu; jf.W[1] = Wt + 12 * WM; jf.bias[1] = ffu_b; jf.resid[1] = usr_feat; jf.out[1] = out_u; jf.mt[1] = 8;
  ff_gemm<<<dim3(8, 16, 2), 256, 0, stream>>>(jf);
  ln_kernel<<<2048, 256, 0, stream>>>(out_v, lnv_g, lnv_b);
  ln_kernel<<<1024, 256, 0, stream>>>(out_u, lnu_g, lnu_b);
}

// Round 8
// 165.864 us; speedup vs baseline: 1.1562x; 1.1562x over previous
//
#include <hip/hip_runtime.h>
#include <hip/hip_bf16.h>

// SegFormerXAttention: B=2, LV=1024, LT=512, D=1024, H=16, DH=64
#define NH 16

typedef __attribute__((ext_vector_type(4))) float f32x4;
typedef __attribute__((ext_vector_type(8))) __bf16 bf16x8;

#define SCL2E 0.18033688011112042f   // (1/sqrt(64)) * log2(e)

__device__ __forceinline__ short f2bs(float f) {
  union { __bf16 h; short s; } x; x.h = (__bf16)f; return x.s;
}
__device__ __forceinline__ unsigned pack2(float a, float b) {
  union { __bf16 h[2]; unsigned u; } x;
  x.h[0] = (__bf16)a; x.h[1] = (__bf16)b; return x.u;
}

__device__ __forceinline__ f32x4 mfma16(bf16x8 a, bf16x8 b, f32x4 c) {
  return __builtin_amdgcn_mfma_f32_16x16x32_bf16(a, b, c, 0, 0, 0);
}

// async global->LDS, 16B per lane. LDS dest = wave-uniform base + lane*16.
__device__ __forceinline__ void gload16(const void* g, void* lds) {
  __builtin_amdgcn_global_load_lds(
      (const __attribute__((address_space(1))) void*)(unsigned long long)(g),
      (__attribute__((address_space(3))) void*)(unsigned)(unsigned long long)(lds),
      16, 0, 0);
}

// ---------------- fused prep: conv vid (2048 blk) + conv usr (1024 blk) + kmask (12 blk) ----------------
__global__ __launch_bounds__(256) void prep_kernel(const float* __restrict__ vf, const float* __restrict__ uf,
                                                   short* __restrict__ Xv, short* __restrict__ Xu,
                                                   const int* __restrict__ vm, const int* __restrict__ um,
                                                   float* __restrict__ kmf) {
  int bid = blockIdx.x;
  if (bid < 2048) {
    int i = bid * 256 + threadIdx.x;
    float4 v = *(const float4*)(vf + (size_t)i * 4);
    *(uint2*)(Xv + (size_t)i * 4) = make_uint2(pack2(v.x, v.y), pack2(v.z, v.w));
  } else if (bid < 3072) {
    int i = (bid - 2048) * 256 + threadIdx.x;
    float4 v = *(const float4*)(uf + (size_t)i * 4);
    *(uint2*)(Xu + (size_t)i * 4) = make_uint2(pack2(v.x, v.y), pack2(v.z, v.w));
  } else {
    int i = (bid - 3072) * 256 + threadIdx.x;
    if (i < 2 * 1536) {
      int b = i / 1536, k = i - b * 1536;
      int valid = (k < 1024) ? vm[b * 1024 + k] : um[b * 512 + (k - 1024)];
      kmf[i] = valid ? 0.0f : -1e35f;
    }
  }
}

// ---------------- weight transpose f32[K,N] -> bf16[N,K] (Q weights pre-scaled) ----------------
struct WPtrs { const float* s[14]; };

__global__ __launch_bounds__(256) void wtrans_kernel(WPtrs p, short* __restrict__ wt) {
  __shared__ float t[64][65];
  int z = blockIdx.z;
  const float* src = p.s[z];
  short* dst = wt + (size_t)z * 1024 * 1024;
  float scl = (z == 0 || z == 3 || z == 6 || z == 9) ? SCL2E : 1.0f;  // Q projections
  int kb = blockIdx.y * 64, nb = blockIdx.x * 64;
  int c = threadIdx.x & 63, r0 = threadIdx.x >> 6;
  #pragma unroll
  for (int i = 0; i < 16; i++) {
    int r = r0 + i * 4;
    t[r][c] = src[(size_t)(kb + r) * 1024 + nb + c];
  }
  __syncthreads();
  #pragma unroll
  for (int i = 0; i < 16; i++) {
    int r = r0 + i * 4;
    dst[(size_t)(nb + r) * 1024 + kb + c] = f2bs(t[c][r] * scl);
  }
}

// ---------------- GEMM staging: tile [128 rows][32 k] bf16 = 8KB ----------------
// Swizzle (both-sides, rule #21): slot (row, c') holds global granule c' ^ (row&3) ^ ((row>>2)&3).
// 4-bit spread kills the 4-way conflict of rows {r, r+4, r+8, r+12} sharing a bank quad.
__device__ __forceinline__ void stage_g(const short* __restrict__ src, int row0, int kt,
                                        short* buf, int tid) {
  int w = tid >> 6;
  #pragma unroll
  for (int i = 0; i < 2; i++) {
    int s = i * 256 + tid;
    int row = s >> 2, c = s & 3;
    int cs = c ^ (row & 3) ^ ((row >> 2) & 3);
    gload16(src + (size_t)(row0 + row) * 1024 + kt + cs * 8,
            buf + (size_t)(i * 256 + w * 64) * 8);
  }
}

// ---------------- 128x128 bf16 GEMM mainloop (K=1024, BK=32, dbuf + global_load_lds) ----------------
__device__ __forceinline__ void gemm_128(const short* __restrict__ X, const short* __restrict__ W,
                                         short* As, short* Bs,
                                         f32x4 (&acc)[4][4], int mb0, int nb0) {
  int tid = threadIdx.x;
  int lane = tid & 63, g = lane >> 4, r16 = lane & 15, w = tid >> 6;
  int wr = (w >> 1) * 64, wc = (w & 1) * 64;
  // row = wr + i*16 + r16: (row&3)=r16&3, ((row>>2)&3)=(r16>>2)&3 (wr,16i contribute 0)
  int cs8 = ((g ^ (r16 & 3) ^ ((r16 >> 2) & 3)) & 3) * 8;
  stage_g(X, mb0, 0, As, tid);
  stage_g(W, nb0, 0, Bs, tid);
  __syncthreads();
  int cur = 0;
  for (int kt = 0; kt < 1024; kt += 32) {
    if (kt + 32 < 1024) {
      stage_g(X, mb0, kt + 32, As + (cur ^ 1) * 4096, tid);
      stage_g(W, nb0, kt + 32, Bs + (cur ^ 1) * 4096, tid);
    }
    const short* a = As + cur * 4096;
    const short* bb = Bs + cur * 4096;
    bf16x8 af[4], bfv[4];
    #pragma unroll
    for (int i = 0; i < 4; i++) af[i]  = *(const bf16x8*)&a[(wr + i * 16 + r16) * 32 + cs8];
    #pragma unroll
    for (int i = 0; i < 4; i++) bfv[i] = *(const bf16x8*)&bb[(wc + i * 16 + r16) * 32 + cs8];
    __builtin_amdgcn_s_setprio(1);
    #pragma unroll
    for (int i = 0; i < 4; i++)
      #pragma unroll
      for (int j = 0; j < 4; j++)
        acc[i][j] = mfma16(af[i], bfv[j], acc[i][j]);
    __builtin_amdgcn_s_setprio(0);
    __syncthreads();
    cur ^= 1;
  }
}

// ---------------- projection GEMMs: 12 jobs, compact 1152-block grid ----------------
// Blocks: jobs 0-5 (vid, M=2048): 128 each; jobs 6-11 (usr, M=1024): 64 each.
struct ProjJobs {
  const short* wt[12];
  short* dst[12];
  const float* bias[12];
  float bscl[12];
  int mode[12];    // 0 = QK layout [B,H,lrows,64] (+row off), 1 = V^T layout [B,H,64,1536] (+col off)
  int lrows[12];
  int off[12];
};

__global__ __launch_bounds__(256) void proj_gemm(const short* __restrict__ Xv,
                                                 const short* __restrict__ Xu, ProjJobs jb) {
  __shared__ short As[2 * 4096];
  __shared__ short Bs[2 * 4096];
  int w0 = blockIdx.x;                       // 1152 blocks
  int f = (w0 & 7) * 144 + (w0 >> 3);        // XCD-chunk swizzle (1152 % 8 == 0)
  int jz, rem, lqShift;
  const short* X;
  if (f < 768) { jz = f >> 7; rem = f & 127; X = Xv; lqShift = 10; }
  else { int f2 = f - 768; jz = 6 + (f2 >> 6); rem = f2 & 63; X = Xu; lqShift = 9; }
  int mb0 = (rem >> 3) * 128, nb0 = (rem & 7) * 128;
  f32x4 acc[4][4];
  f32x4 zf = {0.f, 0.f, 0.f, 0.f};
  #pragma unroll
  for (int i = 0; i < 4; i++)
    #pragma unroll
    for (int j = 0; j < 4; j++) acc[i][j] = zf;
  gemm_128(X, jb.wt[jz], As, Bs, acc, mb0, nb0);

  int tid = threadIdx.x, lane = tid & 63, g = lane >> 4, r16 = lane & 15, w = tid >> 6;
  int wr = (w >> 1) * 64, wc = (w & 1) * 64;
  const float* bias = jb.bias[jz];
  float bscl = jb.bscl[jz];
  short* dst = jb.dst[jz];
  int mode = jb.mode[jz], lrows = jb.lrows[jz], off = jb.off[jz];
  int lqMask = (1 << lqShift) - 1;
  #pragma unroll
  for (int i = 0; i < 4; i++) {
    int m0 = mb0 + wr + i * 16 + g * 4;
    #pragma unroll
    for (int j = 0; j < 4; j++) {
      int n = nb0 + wc + j * 16 + r16;
      float bv = bias[n] * bscl;
      int h = n >> 6, d = n & 63;
      if (mode == 0) {
        #pragma unroll
        for (int r = 0; r < 4; r++) {
          int m = m0 + r;
          int b = m >> lqShift, l = m & lqMask;
          dst[((size_t)(b * NH + h) * lrows + off + l) * 64 + d] = f2bs(acc[i][j][r] + bv);
        }
      } else {
        int b = m0 >> lqShift, l = m0 & lqMask;
        size_t base = ((size_t)(b * NH + h) * 64 + d) * 1536 + off + l;
        *(uint2*)(dst + base) = make_uint2(pack2(acc[i][j][0] + bv, acc[i][j][1] + bv),
                                           pack2(acc[i][j][2] + bv, acc[i][j][3] + bv));
      }
    }
  }
}

// ---------------- FF GEMM: 2 jobs, compact 192-block grid ----------------
struct FfJobs {
  const short* A[2];
  const short* W[2];
  const float* bias[2];
  const float* resid[2];
  float* out[2];
};

__global__ __launch_bounds__(256) void ff_gemm(FfJobs jb) {
  __shared__ short As[2 * 4096];
  __shared__ short Bs[2 * 4096];
  int w0 = blockIdx.x;                       // 192 blocks: job0 128, job1 64
  int f = (w0 & 7) * 24 + (w0 >> 3);
  int jz = (f < 128) ? 0 : 1;
  int rem = (f < 128) ? f : (f - 128);
  int mb0 = (rem >> 3) * 128, nb0 = (rem & 7) * 128;
  f32x4 acc[4][4];
  f32x4 zf = {0.f, 0.f, 0.f, 0.f};
  #pragma unroll
  for (int i = 0; i < 4; i++)
    #pragma unroll
    for (int j = 0; j < 4; j++) acc[i][j] = zf;
  gemm_128(jb.A[jz], jb.W[jz], As, Bs, acc, mb0, nb0);

  int tid = threadIdx.x, lane = tid & 63, g = lane >> 4, r16 = lane & 15, w = tid >> 6;
  int wr = (w >> 1) * 64, wc = (w & 1) * 64;
  const float* bias = jb.bias[jz];
  const float* resid = jb.resid[jz];
  float* out = jb.out[jz];
  #pragma unroll
  for (int i = 0; i < 4; i++) {
    int m0 = mb0 + wr + i * 16 + g * 4;
    #pragma unroll
    for (int j = 0; j < 4; j++) {
      int n = nb0 + wc + j * 16 + r16;
      float bv = bias[n];
      #pragma unroll
      for (int r = 0; r < 4; r++) {
        size_t idx = (size_t)(m0 + r) * 1024 + n;
        out[idx] = acc[i][j][r] + bv + resid[idx];
      }
    }
  }
}

// ---------------- attention staging ----------------
__device__ __forceinline__ void stage_k(const short* __restrict__ Kb, int kb, short* buf, int tid) {
  int w = tid >> 6;
  #pragma unroll
  for (int i = 0; i < 2; i++) {
    int s = i * 256 + tid;
    int row = s >> 3, c = s & 7;
    int cs = c ^ (row & 7);
    gload16(Kb + (size_t)(kb + row) * 64 + cs * 8,
            buf + (size_t)(i * 256 + w * 64) * 8);
  }
}
__device__ __forceinline__ void stage_v(const short* __restrict__ Vb, int kb, short* buf, int tid) {
  int w = tid >> 6;
  #pragma unroll
  for (int i = 0; i < 2; i++) {
    int s = i * 256 + tid;
    int row = s >> 3, c = s & 7;       // row = dh
    int cs = c ^ (row & 7);
    gload16(Vb + (size_t)row * 1536 + kb + cs * 8,
            buf + (size_t)(i * 256 + w * 64) * 8);
  }
}

// ---------------- fused masked attention: key-split 2-way, no-max softmax ----------------
struct AttnArgs {
  const short *Qva, *Qvb, *Kv, *VvT;
  const short *Qta, *Qtb, *Kt, *VtT;
  const int *vmask, *umask;
  const float *kmaskf;
  float *PO, *PL;
};

__global__ __launch_bounds__(256) void attn_kernel(AttnArgs A) {
  __shared__ short Ks[2][64 * 64];   // 16 KB
  __shared__ short Vs[2][64 * 64];   // 16 KB
  __shared__ short Ps[4][16 * 36];   // 4.5 KB per-wave P tile (per-kk reuse), stride 36
  __shared__ float kms[768];         // 3 KB additive mask for this key half

  int w0 = blockIdx.x;               // 1536 blocks
  int fidx = (w0 & 7) * 192 + (w0 >> 3);   // XCD-chunk swizzle
  int half = fidx & 1;
  int slot = fidx >> 1;              // (b*16+h)*24 + xx
  int xx = slot % 24;
  int hs = slot / 24;
  int h = hs & 15;
  int b = hs >> 4;
  bool isV = xx < 16;
  int qt = isV ? xx : (xx - 16);
  int LQ = isV ? 1024 : 512;
  const short* Qa = isV ? A.Qva : A.Qta;
  const short* Qb = isV ? A.Qvb : A.Qtb;
  const short* K  = isV ? A.Kv  : A.Kt;
  const short* VT = isV ? A.VvT : A.VtT;
  const int* qmask = isV ? A.vmask : A.umask;

  int tid = threadIdx.x, w = tid >> 6, lane = tid & 63, g = lane >> 4, r16 = lane & 15;
  int q = qt * 64 + w * 16 + r16;
  size_t bh = (size_t)b * NH + h;
  int k0base = half * 768;

  const short* qpa = Qa + (bh * LQ + q) * 64 + g * 8;
  const short* qpb = Qb + (bh * LQ + q) * 64 + g * 8;
  bf16x8 qa0 = *(const bf16x8*)qpa;
  bf16x8 qa1 = *(const bf16x8*)(qpa + 32);
  bf16x8 qb0 = *(const bf16x8*)qpb;
  bf16x8 qb1 = *(const bf16x8*)(qpb + 32);
  int mqi = qmask[b * LQ + q];

  const short* Kb = K + bh * (size_t)(1536 * 64);
  const short* Vb = VT + bh * (size_t)(64 * 1536);
  const float* kmb = A.kmaskf + b * 1536 + k0base;
  #pragma unroll
  for (int s = tid; s < 192; s += 256)
    *(float4*)&kms[s * 4] = *(const float4*)(kmb + s * 4);

  short* pw = &Ps[w][r16 * 36];
  int sw8 = r16 & 7;

  bf16x8 ones;
  #pragma unroll
  for (int i = 0; i < 8; i++) ones[i] = (__bf16)1.0f;

  f32x4 o[4];
  f32x4 lacc;
  f32x4 zf = {0.f, 0.f, 0.f, 0.f};
  #pragma unroll
  for (int i = 0; i < 4; i++) o[i] = zf;
  lacc = zf;

  stage_k(Kb, k0base, Ks[0], tid);
  stage_v(Vb, k0base, Vs[0], tid);
  __syncthreads();
  int cur = 0;
  for (int kb2 = 0; kb2 < 768; kb2 += 64) {
    if (kb2 + 64 < 768) {
      stage_k(Kb, k0base + kb2 + 64, Ks[cur ^ 1], tid);
      stage_v(Vb, k0base + kb2 + 64, Vs[cur ^ 1], tid);
    }
    const short* Kc = Ks[cur];
    const short* Vc = Vs[cur];
    int gk = k0base + kb2;
    bf16x8 q0 = (gk < 1024) ? qa0 : qb0;
    bf16x8 q1 = (gk < 1024) ? qa1 : qb1;

    float p[16];
    #pragma unroll
    for (int ko = 0; ko < 4; ko++) {
      int krow = ko * 16 + r16;
      bf16x8 k0f = *(const bf16x8*)&Kc[krow * 64 + ((g ^ sw8) * 8)];
      bf16x8 k1f = *(const bf16x8*)&Kc[krow * 64 + (((4 + g) ^ sw8) * 8)];
      __builtin_amdgcn_s_setprio(1);
      f32x4 s = mfma16(k0f, q0, zf);
      s = mfma16(k1f, q1, s);
      __builtin_amdgcn_s_setprio(0);
      float4 kf = *(const float4*)&kms[kb2 + ko * 16 + g * 4];
      p[ko * 4 + 0] = exp2f(mqi ? s[0] + kf.x : 0.0f);
      p[ko * 4 + 1] = exp2f(mqi ? s[1] + kf.y : 0.0f);
      p[ko * 4 + 2] = exp2f(mqi ? s[2] + kf.z : 0.0f);
      p[ko * 4 + 3] = exp2f(mqi ? s[3] + kf.w : 0.0f);
    }

    #pragma unroll
    for (int kk = 0; kk < 2; kk++) {
      int pB = kk * 8;
      *(uint2*)(pw + g * 4) =
          make_uint2(pack2(p[pB + 0], p[pB + 1]), pack2(p[pB + 2], p[pB + 3]));
      *(uint2*)(pw + 16 + g * 4) =
          make_uint2(pack2(p[pB + 4], p[pB + 5]), pack2(p[pB + 6], p[pB + 7]));
      bf16x8 pb = *(const bf16x8*)(pw + g * 8);
      __builtin_amdgcn_s_setprio(1);
      #pragma unroll
      for (int dg = 0; dg < 4; dg++) {
        bf16x8 vfrag = *(const bf16x8*)&Vc[(dg * 16 + r16) * 64 + (((kk * 4 + g) ^ sw8) * 8)];
        o[dg] = mfma16(vfrag, pb, o[dg]);
      }
      lacc = mfma16(ones, pb, lacc);
      __builtin_amdgcn_s_setprio(0);
    }
    __syncthreads();
    cur ^= 1;
  }
  // partials: PO[slot][half][q(64)][d(64)] f32, PL[slot][half][q]
  float* po = A.PO + ((size_t)slot * 2 + half) * 4096 + (w * 16 + r16) * 64;
  #pragma unroll
  for (int dg = 0; dg < 4; dg++)
    *(f32x4*)(po + dg * 16 + g * 4) = o[dg];
  if (g == 0)
    A.PL[((size_t)slot * 2 + half) * 64 + w * 16 + r16] = lacc[0];
}

// ---------------- combine: o = (o0+o1)/(l0+l1), write bf16 AO ----------------
__global__ __launch_bounds__(256) void attn_combine(const float* __restrict__ PO,
                                                    const float* __restrict__ PL,
                                                    short* __restrict__ AOv,
                                                    short* __restrict__ AOu) {
  __shared__ float linv[64];
  int w0 = blockIdx.x;               // 768 blocks
  int slot = (w0 & 7) * 96 + (w0 >> 3);
  int tid = threadIdx.x;
  const float* p0 = PO + (size_t)slot * 2 * 4096;
  const float* p1 = p0 + 4096;
  if (tid < 64) {
    float l = PL[(size_t)slot * 2 * 64 + tid] + PL[((size_t)slot * 2 + 1) * 64 + tid];
    linv[tid] = 1.0f / l;
  }
  __syncthreads();
  int xx = slot % 24;
  int hs = slot / 24;
  int h = hs & 15;
  int b = hs >> 4;
  bool isV = xx < 16;
  int qt = isV ? xx : (xx - 16);
  int LQ = isV ? 1024 : 512;
  short* out = isV ? AOv : AOu;
  #pragma unroll
  for (int it = 0; it < 8; it++) {
    int idx = (it * 256 + tid) * 2;
    int q = idx >> 6, d = idx & 63;
    float2 a = *(const float2*)(p0 + idx);
    float2 c = *(const float2*)(p1 + idx);
    float li = linv[q];
    *(unsigned*)(out + ((size_t)b * LQ + qt * 64 + q) * 1024 + h * 64 + d) =
        pack2((a.x + c.x) * li, (a.y + c.y) * li);
  }
}

// ---------------- merged in-place LayerNorm (3072 rows: 2048 vid + 1024 usr) ----------------
__global__ __launch_bounds__(256) void ln_kernel(float* __restrict__ yv, float* __restrict__ yu,
                                                 const float* __restrict__ gv_, const float* __restrict__ bv_,
                                                 const float* __restrict__ gu_, const float* __restrict__ bu_) {
  __shared__ float sh[8];
  int bid = blockIdx.x;
  bool isV = bid < 2048;
  float* y = isV ? (yv + (size_t)bid * 1024) : (yu + (size_t)(bid - 2048) * 1024);
  const float* gam = isV ? gv_ : gu_;
  const float* bet = isV ? bv_ : bu_;
  int tid = threadIdx.x;
  float4 v = *(const float4*)(y + tid * 4);
  float s = v.x + v.y + v.z + v.w;
  float ss = v.x * v.x + v.y * v.y + v.z * v.z + v.w * v.w;
  #pragma unroll
  for (int off = 32; off >= 1; off >>= 1) {
    s += __shfl_xor(s, off);
    ss += __shfl_xor(ss, off);
  }
  int w = tid >> 6;
  if ((tid & 63) == 0) { sh[w] = s; sh[4 + w] = ss; }
  __syncthreads();
  float st = sh[0] + sh[1] + sh[2] + sh[3];
  float sst = sh[4] + sh[5] + sh[6] + sh[7];
  float mu = st * (1.0f / 1024.0f);
  float var = sst * (1.0f / 1024.0f) - mu * mu;
  float rs = rsqrtf(var + 1e-12f);
  float4 gv = *(const float4*)(gam + tid * 4);
  float4 bv = *(const float4*)(bet + tid * 4);
  float4 ov;
  ov.x = (v.x - mu) * rs * gv.x + bv.x;
  ov.y = (v.y - mu) * rs * gv.y + bv.y;
  ov.z = (v.z - mu) * rs * gv.z + bv.z;
  ov.w = (v.w - mu) * rs * gv.w + bv.w;
  *(float4*)(y + tid * 4) = ov;
}

extern "C" void kernel_launch(void* const* d_in, const int* in_sizes, int n_in,
                              void* d_out, int out_size, void* d_ws, size_t ws_size,
                              hipStream_t stream) {
  const float* vid_feat = (const float*)d_in[0];
  const float* usr_feat = (const float*)d_in[1];
  const int* vid_mask = (const int*)d_in[2];
  const int* usr_mask = (const int*)d_in[3];
  const float* v2v_W = (const float*)d_in[4];
  const float* v2v_b = (const float*)d_in[5];
  const float* t2v_W = (const float*)d_in[6];
  const float* t2v_b = (const float*)d_in[7];
  const float* v2t_W = (const float*)d_in[8];
  const float* v2t_b = (const float*)d_in[9];
  const float* t2t_W = (const float*)d_in[10];
  const float* t2t_b = (const float*)d_in[11];
  const float* ffu_W = (const float*)d_in[12];
  const float* ffu_b = (const float*)d_in[13];
  const float* ffv_W = (const float*)d_in[14];
  const float* ffv_b = (const float*)d_in[15];
  const float* lnu_g = (const float*)d_in[16];
  const float* lnu_b = (const float*)d_in[17];
  const float* lnv_g = (const float*)d_in[18];
  const float* lnv_b = (const float*)d_in[19];

  const size_t WM = 1024 * 1024;
  char* ws = (char*)d_ws;
  size_t off = 0;
  auto alloc = [&](size_t bytes) -> void* {
    void* p = ws + off;
    off += (bytes + 255) & ~(size_t)255;
    return p;
  };
  short* Xv  = (short*)alloc((size_t)2048 * 1024 * 2);
  short* Xu  = (short*)alloc((size_t)1024 * 1024 * 2);
  short* Wt  = (short*)alloc((size_t)14 * WM * 2);
  short* Qva = (short*)alloc((size_t)2 * NH * 1024 * 64 * 2);
  short* Qvb = (short*)alloc((size_t)2 * NH * 1024 * 64 * 2);
  short* Kv  = (short*)alloc((size_t)2 * NH * 1536 * 64 * 2);
  short* VvT = (short*)alloc((size_t)2 * NH * 64 * 1536 * 2);
  short* Qta = (short*)alloc((size_t)2 * NH * 512 * 64 * 2);
  short* Qtb = (short*)alloc((size_t)2 * NH * 512 * 64 * 2);
  short* Kt  = (short*)alloc((size_t)2 * NH * 1536 * 64 * 2);
  short* VtT = (short*)alloc((size_t)2 * NH * 64 * 1536 * 2);
  short* AOv = (short*)alloc((size_t)2048 * 1024 * 2);
  short* AOu = (short*)alloc((size_t)1024 * 1024 * 2);
  float* kmf = (float*)alloc((size_t)2 * 1536 * 4);
  float* PO  = (float*)alloc((size_t)768 * 2 * 4096 * 4);   // 25.2 MB partial O
  float* PL  = (float*)alloc((size_t)768 * 2 * 64 * 4);     // partial l

  // 1) convert activations + additive key mask (one launch)
  prep_kernel<<<3084, 256, 0, stream>>>(vid_feat, usr_feat, Xv, Xu, vid_mask, usr_mask, kmf);

  // 2) transpose weights -> bf16 [N,K] (Q weights scaled by SCL2E)
  WPtrs wp;
  wp.s[0] = v2v_W; wp.s[1] = v2v_W + WM; wp.s[2] = v2v_W + 2 * WM;
  wp.s[3] = t2v_W; wp.s[4] = t2v_W + WM; wp.s[5] = t2v_W + 2 * WM;
  wp.s[6] = v2t_W; wp.s[7] = v2t_W + WM; wp.s[8] = v2t_W + 2 * WM;
  wp.s[9] = t2t_W; wp.s[10] = t2t_W + WM; wp.s[11] = t2t_W + 2 * WM;
  wp.s[12] = ffu_W; wp.s[13] = ffv_W;
  wtrans_kernel<<<dim3(16, 16, 14), 256, 0, stream>>>(wp, Wt);

  // 3) projection GEMMs: 12 jobs, compact 1152-block launch
  ProjJobs jp;
  jp.wt[0] = Wt + 0 * WM;  jp.dst[0] = Qva; jp.bias[0] = v2v_b;        jp.bscl[0] = SCL2E; jp.mode[0] = 0; jp.lrows[0] = 1024; jp.off[0] = 0;
  jp.wt[1] = Wt + 1 * WM;  jp.dst[1] = Kv;  jp.bias[1] = v2v_b + 1024; jp.bscl[1] = 1.0f;  jp.mode[1] = 0; jp.lrows[1] = 1536; jp.off[1] = 0;
  jp.wt[2] = Wt + 2 * WM;  jp.dst[2] = VvT; jp.bias[2] = v2v_b + 2048; jp.bscl[2] = 1.0f;  jp.mode[2] = 1; jp.lrows[2] = 0;    jp.off[2] = 0;
  jp.wt[3] = Wt + 3 * WM;  jp.dst[3] = Qvb; jp.bias[3] = t2v_b;        jp.bscl[3] = SCL2E; jp.mode[3] = 0; jp.lrows[3] = 1024; jp.off[3] = 0;
  jp.wt[4] = Wt + 7 * WM;  jp.dst[4] = Kt;  jp.bias[4] = v2t_b + 1024; jp.bscl[4] = 1.0f;  jp.mode[4] = 0; jp.lrows[4] = 1536; jp.off[4] = 0;
  jp.wt[5] = Wt + 8 * WM;  jp.dst[5] = VtT; jp.bias[5] = v2t_b + 2048; jp.bscl[5] = 1.0f;  jp.mode[5] = 1; jp.lrows[5] = 0;    jp.off[5] = 0;
  jp.wt[6] = Wt + 4 * WM;  jp.dst[6] = Kv;  jp.bias[6] = t2v_b + 1024; jp.bscl[6] = 1.0f;  jp.mode[6] = 0; jp.lrows[6] = 1536; jp.off[6] = 1024;
  jp.wt[7] = Wt + 5 * WM;  jp.dst[7] = VvT; jp.bias[7] = t2v_b + 2048; jp.bscl[7] = 1.0f;  jp.mode[7] = 1; jp.lrows[7] = 0;    jp.off[7] = 1024;
  jp.wt[8] = Wt + 6 * WM;  jp.dst[8] = Qta; jp.bias[8] = v2t_b;        jp.bscl[8] = SCL2E; jp.mode[8] = 0; jp.lrows[8] = 512;  jp.off[8] = 0;
  jp.wt[9] = Wt + 9 * WM;  jp.dst[9] = Qtb; jp.bias[9] = t2t_b;        jp.bscl[9] = SCL2E; jp.mode[9] = 0; jp.lrows[9] = 512;  jp.off[9] = 0;
  jp.wt[10] = Wt + 10 * WM; jp.dst[10] = Kt;  jp.bias[10] = t2t_b + 1024; jp.bscl[10] = 1.0f; jp.mode[10] = 0; jp.lrows[10] = 1536; jp.off[10] = 1024;
  jp.wt[11] = Wt + 11 * WM; jp.dst[11] = VtT; jp.bias[11] = t2t_b + 2048; jp.bscl[11] = 1.0f; jp.mode[11] = 1; jp.lrows[11] = 0;    jp.off[11] = 1024;
  proj_gemm<<<1152, 256, 0, stream>>>(Xv, Xu, jp);

  // 4) attention: key-split 2-way, then combine
  AttnArgs aa;
  aa.Qva = Qva; aa.Qvb = Qvb; aa.Kv = Kv; aa.VvT = VvT;
  aa.Qta = Qta; aa.Qtb = Qtb; aa.Kt = Kt; aa.VtT = VtT;
  aa.vmask = vid_mask; aa.umask = usr_mask; aa.kmaskf = kmf;
  aa.PO = PO; aa.PL = PL;
  attn_kernel<<<1536, 256, 0, stream>>>(aa);
  attn_combine<<<768, 256, 0, stream>>>(PO, PL, AOv, AOu);

  // 5) FF + residual (one 192-block launch), then merged LayerNorm
  float* out_v = (float*)d_out;
  float* out_u = (float*)d_out + (size_t)2 * 1024 * 1024;
  FfJobs jf;
  jf.A[0] = AOv; jf.W[0] = Wt + 13 * WM; jf.bias[0] = ffv_b; jf.resid[0] = vid_feat; jf.out[0] = out_v;
  jf.A[1] = AOu; jf.W[1] = Wt + 12 * WM; jf.bias[1] = ffu_b; jf.resid[1] = usr_feat; jf.out[1] = out_u;
  ff_gemm<<<192, 256, 0, stream>>>(jf);
  ln_kernel<<<3072, 256, 0, stream>>>(out_v, out_u, lnv_g, lnv_b, lnu_g, lnu_b);
}

// Round 9
// 164.366 us; speedup vs baseline: 1.1667x; 1.0091x over previous
//
#include <hip/hip_runtime.h>
#include <hip/hip_bf16.h>

// SegFormerXAttention: B=2, LV=1024, LT=512, D=1024, H=16, DH=64
#define NH 16

typedef __attribute__((ext_vector_type(4))) float f32x4;
typedef __attribute__((ext_vector_type(8))) __bf16 bf16x8;

#define SCL2E 0.18033688011112042f   // (1/sqrt(64)) * log2(e)

__device__ __forceinline__ short f2bs(float f) {
  union { __bf16 h; short s; } x; x.h = (__bf16)f; return x.s;
}
__device__ __forceinline__ unsigned pack2(float a, float b) {
  union { __bf16 h[2]; unsigned u; } x;
  x.h[0] = (__bf16)a; x.h[1] = (__bf16)b; return x.u;
}

__device__ __forceinline__ f32x4 mfma16(bf16x8 a, bf16x8 b, f32x4 c) {
  return __builtin_amdgcn_mfma_f32_16x16x32_bf16(a, b, c, 0, 0, 0);
}

// async global->LDS, 16B per lane. LDS dest = wave-uniform base + lane*16.
__device__ __forceinline__ void gload16(const void* g, void* lds) {
  __builtin_amdgcn_global_load_lds(
      (const __attribute__((address_space(1))) void*)(unsigned long long)(g),
      (__attribute__((address_space(3))) void*)(unsigned)(unsigned long long)(lds),
      16, 0, 0);
}

// ---------------- weight transpose + activation conv + mask, ONE launch ----------------
// z < 14: wtrans plane z. z >= 14: prep block pid = (z-14)*256 + y*16 + x.
struct WPtrs { const float* s[14]; };

__global__ __launch_bounds__(256) void wtrans_prep_kernel(WPtrs p, short* __restrict__ wt,
                                                          const float* __restrict__ vf, const float* __restrict__ uf,
                                                          short* __restrict__ Xv, short* __restrict__ Xu,
                                                          const int* __restrict__ vm, const int* __restrict__ um,
                                                          float* __restrict__ kmf) {
  int z = blockIdx.z;
  if (z >= 14) {
    int pid = (z - 14) * 256 + blockIdx.y * 16 + blockIdx.x;
    if (pid >= 3084) return;
    if (pid < 2048) {
      int i = pid * 256 + threadIdx.x;
      float4 v = *(const float4*)(vf + (size_t)i * 4);
      *(uint2*)(Xv + (size_t)i * 4) = make_uint2(pack2(v.x, v.y), pack2(v.z, v.w));
    } else if (pid < 3072) {
      int i = (pid - 2048) * 256 + threadIdx.x;
      float4 v = *(const float4*)(uf + (size_t)i * 4);
      *(uint2*)(Xu + (size_t)i * 4) = make_uint2(pack2(v.x, v.y), pack2(v.z, v.w));
    } else {
      int i = (pid - 3072) * 256 + threadIdx.x;
      if (i < 2 * 1536) {
        int b = i / 1536, k = i - b * 1536;
        int valid = (k < 1024) ? vm[b * 1024 + k] : um[b * 512 + (k - 1024)];
        kmf[i] = valid ? 0.0f : -1e35f;
      }
    }
    return;
  }
  __shared__ float t[64][65];
  const float* src = p.s[z];
  short* dst = wt + (size_t)z * 1024 * 1024;
  float scl = (z == 0 || z == 3 || z == 6 || z == 9) ? SCL2E : 1.0f;  // Q projections
  int kb = blockIdx.y * 64, nb = blockIdx.x * 64;
  int c = threadIdx.x & 63, r0 = threadIdx.x >> 6;
  #pragma unroll
  for (int i = 0; i < 16; i++) {
    int r = r0 + i * 4;
    t[r][c] = src[(size_t)(kb + r) * 1024 + nb + c];
  }
  __syncthreads();
  #pragma unroll
  for (int i = 0; i < 16; i++) {
    int r = r0 + i * 4;
    dst[(size_t)(nb + r) * 1024 + kb + c] = f2bs(t[c][r] * scl);
  }
}

// ---------------- GEMM staging: tile [128 rows][32 k] bf16 = 8KB ----------------
__device__ __forceinline__ void stage_g(const short* __restrict__ src, int row0, int kt,
                                        short* buf, int tid) {
  int w = tid >> 6;
  #pragma unroll
  for (int i = 0; i < 2; i++) {
    int s = i * 256 + tid;
    int row = s >> 2, c = s & 3;
    int cs = c ^ (row & 3) ^ ((row >> 2) & 3);
    gload16(src + (size_t)(row0 + row) * 1024 + kt + cs * 8,
            buf + (size_t)(i * 256 + w * 64) * 8);
  }
}

// ---------------- 128x128 bf16 GEMM mainloop: SINGLE barrier per K-iter ----------------
// Order: barrier -> ds_read frags(cur) -> issue stage(cur^1) -> MFMA.
// Barrier's per-wave vmcnt(0)+lgkmcnt(0) drain guarantees: stage(t-1) landed before
// reads of cur; all waves' reads of cur^1 drained before it is re-staged (WAR-safe).
__device__ __forceinline__ void gemm_128(const short* __restrict__ X, const short* __restrict__ W,
                                         short* As, short* Bs,
                                         f32x4 (&acc)[4][4], int mb0, int nb0) {
  int tid = threadIdx.x;
  int lane = tid & 63, g = lane >> 4, r16 = lane & 15, w = tid >> 6;
  int wr = (w >> 1) * 64, wc = (w & 1) * 64;
  int cs8 = ((g ^ (r16 & 3) ^ ((r16 >> 2) & 3)) & 3) * 8;
  stage_g(X, mb0, 0, As, tid);
  stage_g(W, nb0, 0, Bs, tid);
  int cur = 0;
  for (int kt = 0; kt < 1024; kt += 32) {
    __syncthreads();
    const short* a = As + cur * 4096;
    const short* bb = Bs + cur * 4096;
    bf16x8 af[4], bfv[4];
    #pragma unroll
    for (int i = 0; i < 4; i++) af[i]  = *(const bf16x8*)&a[(wr + i * 16 + r16) * 32 + cs8];
    #pragma unroll
    for (int i = 0; i < 4; i++) bfv[i] = *(const bf16x8*)&bb[(wc + i * 16 + r16) * 32 + cs8];
    if (kt + 32 < 1024) {
      stage_g(X, mb0, kt + 32, As + (cur ^ 1) * 4096, tid);
      stage_g(W, nb0, kt + 32, Bs + (cur ^ 1) * 4096, tid);
    }
    __builtin_amdgcn_s_setprio(1);
    #pragma unroll
    for (int i = 0; i < 4; i++)
      #pragma unroll
      for (int j = 0; j < 4; j++)
        acc[i][j] = mfma16(af[i], bfv[j], acc[i][j]);
    __builtin_amdgcn_s_setprio(0);
    cur ^= 1;
  }
}

// ---------------- projection GEMMs: 12 jobs, compact 1152-block grid ----------------
struct ProjJobs {
  const short* wt[12];
  short* dst[12];
  const float* bias[12];
  float bscl[12];
  int mode[12];    // 0 = QK layout [B,H,lrows,64] (+row off), 1 = V^T layout [B,H,64,1536] (+col off)
  int lrows[12];
  int off[12];
};

__global__ __launch_bounds__(256) void proj_gemm(const short* __restrict__ Xv,
                                                 const short* __restrict__ Xu, ProjJobs jb) {
  __shared__ short As[2 * 4096];
  __shared__ short Bs[2 * 4096];
  int w0 = blockIdx.x;                       // 1152 blocks
  int f = (w0 & 7) * 144 + (w0 >> 3);        // XCD-chunk swizzle (1152 % 8 == 0)
  int jz, rem, lqShift;
  const short* X;
  if (f < 768) { jz = f >> 7; rem = f & 127; X = Xv; lqShift = 10; }
  else { int f2 = f - 768; jz = 6 + (f2 >> 6); rem = f2 & 63; X = Xu; lqShift = 9; }
  int mb0 = (rem >> 3) * 128, nb0 = (rem & 7) * 128;
  f32x4 acc[4][4];
  f32x4 zf = {0.f, 0.f, 0.f, 0.f};
  #pragma unroll
  for (int i = 0; i < 4; i++)
    #pragma unroll
    for (int j = 0; j < 4; j++) acc[i][j] = zf;
  gemm_128(X, jb.wt[jz], As, Bs, acc, mb0, nb0);

  int tid = threadIdx.x, lane = tid & 63, g = lane >> 4, r16 = lane & 15, w = tid >> 6;
  int wr = (w >> 1) * 64, wc = (w & 1) * 64;
  const float* bias = jb.bias[jz];
  float bscl = jb.bscl[jz];
  short* dst = jb.dst[jz];
  int mode = jb.mode[jz], lrows = jb.lrows[jz], off = jb.off[jz];
  int lqMask = (1 << lqShift) - 1;
  #pragma unroll
  for (int i = 0; i < 4; i++) {
    int m0 = mb0 + wr + i * 16 + g * 4;
    #pragma unroll
    for (int j = 0; j < 4; j++) {
      int n = nb0 + wc + j * 16 + r16;
      float bv = bias[n] * bscl;
      int h = n >> 6, d = n & 63;
      if (mode == 0) {
        #pragma unroll
        for (int r = 0; r < 4; r++) {
          int m = m0 + r;
          int b = m >> lqShift, l = m & lqMask;
          dst[((size_t)(b * NH + h) * lrows + off + l) * 64 + d] = f2bs(acc[i][j][r] + bv);
        }
      } else {
        int b = m0 >> lqShift, l = m0 & lqMask;
        size_t base = ((size_t)(b * NH + h) * 64 + d) * 1536 + off + l;
        *(uint2*)(dst + base) = make_uint2(pack2(acc[i][j][0] + bv, acc[i][j][1] + bv),
                                           pack2(acc[i][j][2] + bv, acc[i][j][3] + bv));
      }
    }
  }
}

// ---------------- FF GEMM: 2 jobs, compact 192-block grid ----------------
struct FfJobs {
  const short* A[2];
  const short* W[2];
  const float* bias[2];
  const float* resid[2];
  float* out[2];
};

__global__ __launch_bounds__(256) void ff_gemm(FfJobs jb) {
  __shared__ short As[2 * 4096];
  __shared__ short Bs[2 * 4096];
  int w0 = blockIdx.x;                       // 192 blocks: job0 128, job1 64
  int f = (w0 & 7) * 24 + (w0 >> 3);
  int jz = (f < 128) ? 0 : 1;
  int rem = (f < 128) ? f : (f - 128);
  int mb0 = (rem >> 3) * 128, nb0 = (rem & 7) * 128;
  f32x4 acc[4][4];
  f32x4 zf = {0.f, 0.f, 0.f, 0.f};
  #pragma unroll
  for (int i = 0; i < 4; i++)
    #pragma unroll
    for (int j = 0; j < 4; j++) acc[i][j] = zf;
  gemm_128(jb.A[jz], jb.W[jz], As, Bs, acc, mb0, nb0);

  int tid = threadIdx.x, lane = tid & 63, g = lane >> 4, r16 = lane & 15, w = tid >> 6;
  int wr = (w >> 1) * 64, wc = (w & 1) * 64;
  const float* bias = jb.bias[jz];
  const float* resid = jb.resid[jz];
  float* out = jb.out[jz];
  #pragma unroll
  for (int i = 0; i < 4; i++) {
    int m0 = mb0 + wr + i * 16 + g * 4;
    #pragma unroll
    for (int j = 0; j < 4; j++) {
      int n = nb0 + wc + j * 16 + r16;
      float bv = bias[n];
      #pragma unroll
      for (int r = 0; r < 4; r++) {
        size_t idx = (size_t)(m0 + r) * 1024 + n;
        out[idx] = acc[i][j][r] + bv + resid[idx];
      }
    }
  }
}

// ---------------- attention staging ----------------
__device__ __forceinline__ void stage_k(const short* __restrict__ Kb, int kb, short* buf, int tid) {
  int w = tid >> 6;
  #pragma unroll
  for (int i = 0; i < 2; i++) {
    int s = i * 256 + tid;
    int row = s >> 3, c = s & 7;
    int cs = c ^ (row & 7);
    gload16(Kb + (size_t)(kb + row) * 64 + cs * 8,
            buf + (size_t)(i * 256 + w * 64) * 8);
  }
}
__device__ __forceinline__ void stage_v(const short* __restrict__ Vb, int kb, short* buf, int tid) {
  int w = tid >> 6;
  #pragma unroll
  for (int i = 0; i < 2; i++) {
    int s = i * 256 + tid;
    int row = s >> 3, c = s & 7;       // row = dh
    int cs = c ^ (row & 7);
    gload16(Vb + (size_t)row * 1536 + kb + cs * 8,
            buf + (size_t)(i * 256 + w * 64) * 8);
  }
}

// ---------------- fused masked attention: key-split 2-way, no-max softmax, 1 barrier/iter ----------------
struct AttnArgs {
  const short *Qva, *Qvb, *Kv, *VvT;
  const short *Qta, *Qtb, *Kt, *VtT;
  const int *vmask, *umask;
  const float *kmaskf;
  float *PO, *PL;
};

__global__ __launch_bounds__(256) void attn_kernel(AttnArgs A) {
  __shared__ short Ks[2][64 * 64];   // 16 KB
  __shared__ short Vs[2][64 * 64];   // 16 KB
  __shared__ short Ps[4][16 * 36];   // 4.5 KB per-wave P tile (no cross-wave hazard)
  __shared__ float kms[768];         // 3 KB additive mask for this key half

  int w0 = blockIdx.x;               // 1536 blocks
  int fidx = (w0 & 7) * 192 + (w0 >> 3);   // XCD-chunk swizzle
  int half = fidx & 1;
  int slot = fidx >> 1;              // (b*16+h)*24 + xx
  int xx = slot % 24;
  int hs = slot / 24;
  int h = hs & 15;
  int b = hs >> 4;
  bool isV = xx < 16;
  int qt = isV ? xx : (xx - 16);
  int LQ = isV ? 1024 : 512;
  const short* Qa = isV ? A.Qva : A.Qta;
  const short* Qb = isV ? A.Qvb : A.Qtb;
  const short* K  = isV ? A.Kv  : A.Kt;
  const short* VT = isV ? A.VvT : A.VtT;
  const int* qmask = isV ? A.vmask : A.umask;

  int tid = threadIdx.x, w = tid >> 6, lane = tid & 63, g = lane >> 4, r16 = lane & 15;
  int q = qt * 64 + w * 16 + r16;
  size_t bh = (size_t)b * NH + h;
  int k0base = half * 768;

  const short* qpa = Qa + (bh * LQ + q) * 64 + g * 8;
  const short* qpb = Qb + (bh * LQ + q) * 64 + g * 8;
  bf16x8 qa0 = *(const bf16x8*)qpa;
  bf16x8 qa1 = *(const bf16x8*)(qpa + 32);
  bf16x8 qb0 = *(const bf16x8*)qpb;
  bf16x8 qb1 = *(const bf16x8*)(qpb + 32);
  int mqi = qmask[b * LQ + q];

  const short* Kb = K + bh * (size_t)(1536 * 64);
  const short* Vb = VT + bh * (size_t)(64 * 1536);
  const float* kmb = A.kmaskf + b * 1536 + k0base;
  #pragma unroll
  for (int s = tid; s < 192; s += 256)
    *(float4*)&kms[s * 4] = *(const float4*)(kmb + s * 4);

  short* pw = &Ps[w][r16 * 36];
  int sw8 = r16 & 7;

  bf16x8 ones;
  #pragma unroll
  for (int i = 0; i < 8; i++) ones[i] = (__bf16)1.0f;

  f32x4 o[4];
  f32x4 lacc;
  f32x4 zf = {0.f, 0.f, 0.f, 0.f};
  #pragma unroll
  for (int i = 0; i < 4; i++) o[i] = zf;
  lacc = zf;

  stage_k(Kb, k0base, Ks[0], tid);
  stage_v(Vb, k0base, Vs[0], tid);
  int cur = 0;
  for (int kb2 = 0; kb2 < 768; kb2 += 64) {
    __syncthreads();                 // drains stage(t-1) + all waves' reads of cur^1
    const short* Kc = Ks[cur];
    const short* Vc = Vs[cur];
    int gk = k0base + kb2;
    bf16x8 q0 = (gk < 1024) ? qa0 : qb0;
    bf16x8 q1 = (gk < 1024) ? qa1 : qb1;

    float p[16];
    #pragma unroll
    for (int ko = 0; ko < 4; ko++) {
      int krow = ko * 16 + r16;
      bf16x8 k0f = *(const bf16x8*)&Kc[krow * 64 + ((g ^ sw8) * 8)];
      bf16x8 k1f = *(const bf16x8*)&Kc[krow * 64 + (((4 + g) ^ sw8) * 8)];
      __builtin_amdgcn_s_setprio(1);
      f32x4 s = mfma16(k0f, q0, zf);
      s = mfma16(k1f, q1, s);
      __builtin_amdgcn_s_setprio(0);
      float4 kf = *(const float4*)&kms[kb2 + ko * 16 + g * 4];
      p[ko * 4 + 0] = exp2f(mqi ? s[0] + kf.x : 0.0f);
      p[ko * 4 + 1] = exp2f(mqi ? s[1] + kf.y : 0.0f);
      p[ko * 4 + 2] = exp2f(mqi ? s[2] + kf.z : 0.0f);
      p[ko * 4 + 3] = exp2f(mqi ? s[3] + kf.w : 0.0f);
    }

    // issue next tile's staging after QK reads; overlaps with softmax + PV
    if (kb2 + 64 < 768) {
      stage_k(Kb, k0base + kb2 + 64, Ks[cur ^ 1], tid);
      stage_v(Vb, k0base + kb2 + 64, Vs[cur ^ 1], tid);
    }

    #pragma unroll
    for (int kk = 0; kk < 2; kk++) {
      int pB = kk * 8;
      *(uint2*)(pw + g * 4) =
          make_uint2(pack2(p[pB + 0], p[pB + 1]), pack2(p[pB + 2], p[pB + 3]));
      *(uint2*)(pw + 16 + g * 4) =
          make_uint2(pack2(p[pB + 4], p[pB + 5]), pack2(p[pB + 6], p[pB + 7]));
      bf16x8 pb = *(const bf16x8*)(pw + g * 8);
      __builtin_amdgcn_s_setprio(1);
      #pragma unroll
      for (int dg = 0; dg < 4; dg++) {
        bf16x8 vfrag = *(const bf16x8*)&Vc[(dg * 16 + r16) * 64 + (((kk * 4 + g) ^ sw8) * 8)];
        o[dg] = mfma16(vfrag, pb, o[dg]);
      }
      lacc = mfma16(ones, pb, lacc);
      __builtin_amdgcn_s_setprio(0);
    }
    cur ^= 1;
  }
  // partials: PO[slot][half][q(64)][d(64)] f32, PL[slot][half][q]
  float* po = A.PO + ((size_t)slot * 2 + half) * 4096 + (w * 16 + r16) * 64;
  #pragma unroll
  for (int dg = 0; dg < 4; dg++)
    *(f32x4*)(po + dg * 16 + g * 4) = o[dg];
  if (g == 0)
    A.PL[((size_t)slot * 2 + half) * 64 + w * 16 + r16] = lacc[0];
}

// ---------------- combine: o = (o0+o1)/(l0+l1), write bf16 AO ----------------
__global__ __launch_bounds__(256) void attn_combine(const float* __restrict__ PO,
                                                    const float* __restrict__ PL,
                                                    short* __restrict__ AOv,
                                                    short* __restrict__ AOu) {
  __shared__ float linv[64];
  int w0 = blockIdx.x;               // 768 blocks
  int slot = (w0 & 7) * 96 + (w0 >> 3);
  int tid = threadIdx.x;
  const float* p0 = PO + (size_t)slot * 2 * 4096;
  const float* p1 = p0 + 4096;
  if (tid < 64) {
    float l = PL[(size_t)slot * 2 * 64 + tid] + PL[((size_t)slot * 2 + 1) * 64 + tid];
    linv[tid] = 1.0f / l;
  }
  __syncthreads();
  int xx = slot % 24;
  int hs = slot / 24;
  int h = hs & 15;
  int b = hs >> 4;
  bool isV = xx < 16;
  int qt = isV ? xx : (xx - 16);
  int LQ = isV ? 1024 : 512;
  short* out = isV ? AOv : AOu;
  #pragma unroll
  for (int it = 0; it < 8; it++) {
    int idx = (it * 256 + tid) * 2;
    int q = idx >> 6, d = idx & 63;
    float2 a = *(const float2*)(p0 + idx);
    float2 c = *(const float2*)(p1 + idx);
    float li = linv[q];
    *(unsigned*)(out + ((size_t)b * LQ + qt * 64 + q) * 1024 + h * 64 + d) =
        pack2((a.x + c.x) * li, (a.y + c.y) * li);
  }
}

// ---------------- merged in-place LayerNorm (3072 rows: 2048 vid + 1024 usr) ----------------
__global__ __launch_bounds__(256) void ln_kernel(float* __restrict__ yv, float* __restrict__ yu,
                                                 const float* __restrict__ gv_, const float* __restrict__ bv_,
                                                 const float* __restrict__ gu_, const float* __restrict__ bu_) {
  __shared__ float sh[8];
  int bid = blockIdx.x;
  bool isV = bid < 2048;
  float* y = isV ? (yv + (size_t)bid * 1024) : (yu + (size_t)(bid - 2048) * 1024);
  const float* gam = isV ? gv_ : gu_;
  const float* bet = isV ? bv_ : bu_;
  int tid = threadIdx.x;
  float4 v = *(const float4*)(y + tid * 4);
  float s = v.x + v.y + v.z + v.w;
  float ss = v.x * v.x + v.y * v.y + v.z * v.z + v.w * v.w;
  #pragma unroll
  for (int off = 32; off >= 1; off >>= 1) {
    s += __shfl_xor(s, off);
    ss += __shfl_xor(ss, off);
  }
  int w = tid >> 6;
  if ((tid & 63) == 0) { sh[w] = s; sh[4 + w] = ss; }
  __syncthreads();
  float st = sh[0] + sh[1] + sh[2] + sh[3];
  float sst = sh[4] + sh[5] + sh[6] + sh[7];
  float mu = st * (1.0f / 1024.0f);
  float var = sst * (1.0f / 1024.0f) - mu * mu;
  float rs = rsqrtf(var + 1e-12f);
  float4 gv = *(const float4*)(gam + tid * 4);
  float4 bv = *(const float4*)(bet + tid * 4);
  float4 ov;
  ov.x = (v.x - mu) * rs * gv.x + bv.x;
  ov.y = (v.y - mu) * rs * gv.y + bv.y;
  ov.z = (v.z - mu) * rs * gv.z + bv.z;
  ov.w = (v.w - mu) * rs * gv.w + bv.w;
  *(float4*)(y + tid * 4) = ov;
}

extern "C" void kernel_launch(void* const* d_in, const int* in_sizes, int n_in,
                              void* d_out, int out_size, void* d_ws, size_t ws_size,
                              hipStream_t stream) {
  const float* vid_feat = (const float*)d_in[0];
  const float* usr_feat = (const float*)d_in[1];
  const int* vid_mask = (const int*)d_in[2];
  const int* usr_mask = (const int*)d_in[3];
  const float* v2v_W = (const float*)d_in[4];
  const float* v2v_b = (const float*)d_in[5];
  const float* t2v_W = (const float*)d_in[6];
  const float* t2v_b = (const float*)d_in[7];
  const float* v2t_W = (const float*)d_in[8];
  const float* v2t_b = (const float*)d_in[9];
  const float* t2t_W = (const float*)d_in[10];
  const float* t2t_b = (const float*)d_in[11];
  const float* ffu_W = (const float*)d_in[12];
  const float* ffu_b = (const float*)d_in[13];
  const float* ffv_W = (const float*)d_in[14];
  const float* ffv_b = (const float*)d_in[15];
  const float* lnu_g = (const float*)d_in[16];
  const float* lnu_b = (const float*)d_in[17];
  const float* lnv_g = (const float*)d_in[18];
  const float* lnv_b = (const float*)d_in[19];

  const size_t WM = 1024 * 1024;
  char* ws = (char*)d_ws;
  size_t off = 0;
  auto alloc = [&](size_t bytes) -> void* {
    void* p = ws + off;
    off += (bytes + 255) & ~(size_t)255;
    return p;
  };
  short* Xv  = (short*)alloc((size_t)2048 * 1024 * 2);
  short* Xu  = (short*)alloc((size_t)1024 * 1024 * 2);
  short* Wt  = (short*)alloc((size_t)14 * WM * 2);
  short* Qva = (short*)alloc((size_t)2 * NH * 1024 * 64 * 2);
  short* Qvb = (short*)alloc((size_t)2 * NH * 1024 * 64 * 2);
  short* Kv  = (short*)alloc((size_t)2 * NH * 1536 * 64 * 2);
  short* VvT = (short*)alloc((size_t)2 * NH * 64 * 1536 * 2);
  short* Qta = (short*)alloc((size_t)2 * NH * 512 * 64 * 2);
  short* Qtb = (short*)alloc((size_t)2 * NH * 512 * 64 * 2);
  short* Kt  = (short*)alloc((size_t)2 * NH * 1536 * 64 * 2);
  short* VtT = (short*)alloc((size_t)2 * NH * 64 * 1536 * 2);
  short* AOv = (short*)alloc((size_t)2048 * 1024 * 2);
  short* AOu = (short*)alloc((size_t)1024 * 1024 * 2);
  float* kmf = (float*)alloc((size_t)2 * 1536 * 4);
  float* PO  = (float*)alloc((size_t)768 * 2 * 4096 * 4);   // 25.2 MB partial O
  float* PL  = (float*)alloc((size_t)768 * 2 * 64 * 4);     // partial l

  // 1+2) weights transpose + activation conv + mask, one launch
  WPtrs wp;
  wp.s[0] = v2v_W; wp.s[1] = v2v_W + WM; wp.s[2] = v2v_W + 2 * WM;
  wp.s[3] = t2v_W; wp.s[4] = t2v_W + WM; wp.s[5] = t2v_W + 2 * WM;
  wp.s[6] = v2t_W; wp.s[7] = v2t_W + WM; wp.s[8] = v2t_W + 2 * WM;
  wp.s[9] = t2t_W; wp.s[10] = t2t_W + WM; wp.s[11] = t2t_W + 2 * WM;
  wp.s[12] = ffu_W; wp.s[13] = ffv_W;
  wtrans_prep_kernel<<<dim3(16, 16, 27), 256, 0, stream>>>(wp, Wt, vid_feat, usr_feat,
                                                           Xv, Xu, vid_mask, usr_mask, kmf);

  // 3) projection GEMMs: 12 jobs, compact 1152-block launch
  ProjJobs jp;
  jp.wt[0] = Wt + 0 * WM;  jp.dst[0] = Qva; jp.bias[0] = v2v_b;        jp.bscl[0] = SCL2E; jp.mode[0] = 0; jp.lrows[0] = 1024; jp.off[0] = 0;
  jp.wt[1] = Wt + 1 * WM;  jp.dst[1] = Kv;  jp.bias[1] = v2v_b + 1024; jp.bscl[1] = 1.0f;  jp.mode[1] = 0; jp.lrows[1] = 1536; jp.off[1] = 0;
  jp.wt[2] = Wt + 2 * WM;  jp.dst[2] = VvT; jp.bias[2] = v2v_b + 2048; jp.bscl[2] = 1.0f;  jp.mode[2] = 1; jp.lrows[2] = 0;    jp.off[2] = 0;
  jp.wt[3] = Wt + 3 * WM;  jp.dst[3] = Qvb; jp.bias[3] = t2v_b;        jp.bscl[3] = SCL2E; jp.mode[3] = 0; jp.lrows[3] = 1024; jp.off[3] = 0;
  jp.wt[4] = Wt + 7 * WM;  jp.dst[4] = Kt;  jp.bias[4] = v2t_b + 1024; jp.bscl[4] = 1.0f;  jp.mode[4] = 0; jp.lrows[4] = 1536; jp.off[4] = 0;
  jp.wt[5] = Wt + 8 * WM;  jp.dst[5] = VtT; jp.bias[5] = v2t_b + 2048; jp.bscl[5] = 1.0f;  jp.mode[5] = 1; jp.lrows[5] = 0;    jp.off[5] = 0;
  jp.wt[6] = Wt + 4 * WM;  jp.dst[6] = Kv;  jp.bias[6] = t2v_b + 1024; jp.bscl[6] = 1.0f;  jp.mode[6] = 0; jp.lrows[6] = 1536; jp.off[6] = 1024;
  jp.wt[7] = Wt + 5 * WM;  jp.dst[7] = VvT; jp.bias[7] = t2v_b + 2048; jp.bscl[7] = 1.0f;  jp.mode[7] = 1; jp.lrows[7] = 0;    jp.off[7] = 1024;
  jp.wt[8] = Wt + 6 * WM;  jp.dst[8] = Qta; jp.bias[8] = v2t_b;        jp.bscl[8] = SCL2E; jp.mode[8] = 0; jp.lrows[8] = 512;  jp.off[8] = 0;
  jp.wt[9] = Wt + 9 * WM;  jp.dst[9] = Qtb; jp.bias[9] = t2t_b;        jp.bscl[9] = SCL2E; jp.mode[9] = 0; jp.lrows[9] = 512;  jp.off[9] = 0;
  jp.wt[10] = Wt + 10 * WM; jp.dst[10] = Kt;  jp.bias[10] = t2t_b + 1024; jp.bscl[10] = 1.0f; jp.mode[10] = 0; jp.lrows[10] = 1536; jp.off[10] = 1024;
  jp.wt[11] = Wt + 11 * WM; jp.dst[11] = VtT; jp.bias[11] = t2t_b + 2048; jp.bscl[11] = 1.0f; jp.mode[11] = 1; jp.lrows[11] = 0;    jp.off[11] = 1024;
  proj_gemm<<<1152, 256, 0, stream>>>(Xv, Xu, jp);

  // 4) attention: key-split 2-way, then combine
  AttnArgs aa;
  aa.Qva = Qva; aa.Qvb = Qvb; aa.Kv = Kv; aa.VvT = VvT;
  aa.Qta = Qta; aa.Qtb = Qtb; aa.Kt = Kt; aa.VtT = VtT;
  aa.vmask = vid_mask; aa.umask = usr_mask; aa.kmaskf = kmf;
  aa.PO = PO; aa.PL = PL;
  attn_kernel<<<1536, 256, 0, stream>>>(aa);
  attn_combine<<<768, 256, 0, stream>>>(PO, PL, AOv, AOu);

  // 5) FF + residual (one 192-block launch), then merged LayerNorm
  float* out_v = (float*)d_out;
  float* out_u = (float*)d_out + (size_t)2 * 1024 * 1024;
  FfJobs jf;
  jf.A[0] = AOv; jf.W[0] = Wt + 13 * WM; jf.bias[0] = ffv_b; jf.resid[0] = vid_feat; jf.out[0] = out_v;
  jf.A[1] = AOu; jf.W[1] = Wt + 12 * WM; jf.bias[1] = ffu_b; jf.resid[1] = usr_feat; jf.out[1] = out_u;
  ff_gemm<<<192, 256, 0, stream>>>(jf);
  ln_kernel<<<3072, 256, 0, stream>>>(out_v, out_u, lnv_g, lnv_b, lnu_g, lnu_b);
}